// Round 3
// baseline (435.967 us; speedup 1.0000x reference)
//
#include <hip/hip_runtime.h>
#include <hip/hip_bf16.h>
#include <cstdint>
#include <cstddef>

// Transformer block: B=2, T=2048, C=1024, H=16, HD=64.
// bf16 MFMA for all GEMM-shaped compute; fp32 for LN stats / softmax sums / residuals.
// R3: split-K (atomicAdd partials) for the N=1024 GEMMs (proj, fc2) — they had only
// 256 blocks = 1 block/CU = 10% occupancy and stalled on every barrier drain.
#define B_  2
#define T_  2048
#define C_  1024
#define H_  16
#define HD_ 64
#define M_TOT 4096   // B*T

typedef __bf16 bf16x8 __attribute__((ext_vector_type(8)));
typedef float  f32x4  __attribute__((ext_vector_type(4)));
typedef unsigned short u16;

__device__ __forceinline__ u16 f2bf(float f) {
  __hip_bfloat16 h = __float2bfloat16(f);
  return __builtin_bit_cast(u16, h);
}

// async global->LDS, 16B per lane; LDS dest is wave-uniform base + lane*16.
__device__ __forceinline__ void async_cp16(const u16* g, u16* l) {
  __builtin_amdgcn_global_load_lds(
      (const __attribute__((address_space(1))) void*)g,
      (__attribute__((address_space(3))) void*)l, 16, 0, 0);
}

// gelu_tanh: 0.5*x*(1+tanh z) == x * sigmoid(2z); overflow-safe via negative exp.
__device__ __forceinline__ float gelu_f(float x) {
  const float z = 0.7978845608028654f * (x + 0.044715f * x * x * x);
  return x / (1.0f + __expf(-2.0f * z));
}

// ---------------- LayerNorm (fp32 in -> bf16 out), one block per row ----------------
__global__ __launch_bounds__(256) void ln_bf16_kernel(
    const float* __restrict__ x, const float* __restrict__ g,
    const float* __restrict__ b, u16* __restrict__ out) {
  const int row = blockIdx.x;
  const int tid = threadIdx.x;
  const float4 v = reinterpret_cast<const float4*>(x)[row * 256 + tid];
  float s  = v.x + v.y + v.z + v.w;
  float sq = v.x * v.x + v.y * v.y + v.z * v.z + v.w * v.w;
#pragma unroll
  for (int off = 32; off > 0; off >>= 1) {
    s  += __shfl_xor(s, off);
    sq += __shfl_xor(sq, off);
  }
  __shared__ float red[8];
  const int wave = tid >> 6;
  if ((tid & 63) == 0) { red[wave] = s; red[4 + wave] = sq; }
  __syncthreads();
  s  = red[0] + red[1] + red[2] + red[3];
  sq = red[4] + red[5] + red[6] + red[7];
  const float mu   = s * (1.0f / 1024.0f);
  const float rstd = rsqrtf(sq * (1.0f / 1024.0f) - mu * mu + 1e-5f);
  const float4 gv = reinterpret_cast<const float4*>(g)[tid];
  const float4 bv = reinterpret_cast<const float4*>(b)[tid];
  ushort4 o;
  o.x = f2bf((v.x - mu) * rstd * gv.x + bv.x);
  o.y = f2bf((v.y - mu) * rstd * gv.y + bv.y);
  o.z = f2bf((v.z - mu) * rstd * gv.z + bv.z);
  o.w = f2bf((v.w - mu) * rstd * gv.w + bv.w);
  reinterpret_cast<ushort4*>(out)[row * 256 + tid] = o;
}

// ---------------- W[K][N] fp32 -> Wt[N][K] bf16 (tiled transpose+convert) ----------------
__global__ __launch_bounds__(256) void transpose_bf16_kernel(
    const float* __restrict__ W, u16* __restrict__ Wt, int K, int N) {
  __shared__ float tile[32][33];
  const int n0 = blockIdx.x * 32, k0 = blockIdx.y * 32;
  const int tx = threadIdx.x & 31;
  const int ty = threadIdx.x >> 5;  // 0..7
#pragma unroll
  for (int i = 0; i < 4; ++i)
    tile[ty + 8 * i][tx] = W[(k0 + ty + 8 * i) * (size_t)N + n0 + tx];
  __syncthreads();
#pragma unroll
  for (int i = 0; i < 4; ++i)
    Wt[(n0 + ty + 8 * i) * (size_t)K + k0 + tx] = f2bf(tile[tx][ty + 8 * i]);
}

// ---------------- out[m][n] = resid[m][n] + bias[n]  (seeds split-K accumulation) ---------
__global__ __launch_bounds__(256) void init_bias_resid_kernel(
    const float* __restrict__ resid, const float* __restrict__ bias,
    float* __restrict__ out, int N4) {
  const size_t i = (size_t)blockIdx.x * 256 + threadIdx.x;
  const float4 r = reinterpret_cast<const float4*>(resid)[i];
  const float4 bb = reinterpret_cast<const float4*>(bias)[i % N4];
  float4 o;
  o.x = r.x + bb.x; o.y = r.y + bb.y; o.z = r.z + bb.z; o.w = r.w + bb.w;
  reinterpret_cast<float4*>(out)[i] = o;
}

// ---------------- bf16 MFMA GEMM: C[M,N] = A[M,K] @ Bt[N,K]^T, fused epilogues -------------
// MODE 0: +bias, gelu -> bf16 out                      (fc)
// MODE 1: split-K partial -> atomicAdd fp32 out        (proj, fc2; out pre-seeded)
// MODE 3: +bias, scatter q(scaled)/k [B,H,T,HD], v transposed [B,H,HD,T]  (qkv)
template <int MODE>
__global__ __launch_bounds__(256, 2) void gemm_kernel(
    const u16* __restrict__ A, const u16* __restrict__ Bt,
    const float* __restrict__ bias,
    float* __restrict__ outf, u16* __restrict__ outb,
    u16* __restrict__ qo, u16* __restrict__ ko, u16* __restrict__ vto,
    int M, int N, int K, int kchunk) {
  __shared__ __align__(16) u16 As[128 * 32];
  __shared__ __align__(16) u16 Bs[128 * 32];
  const int tid  = threadIdx.x;
  const int wave = tid >> 6, lane = tid & 63;
  const int col  = lane & 15, quad = lane >> 4;
  const int wm   = wave >> 1, wn = wave & 1;
  const int bn = blockIdx.x, bm = blockIdx.y;
  const int kb = blockIdx.z * kchunk, ke = kb + kchunk;

  const int ar = bm * 128 + wave * 32 + (lane >> 2);
  const int br = bn * 128 + wave * 32 + (lane >> 2);
  const int kc = (lane & 3) * 8;
  const u16* ap = A  + (size_t)ar * K + kc;
  const u16* bp = Bt + (size_t)br * K + kc;
  u16* as_dst = As + wave * 1024;
  u16* bs_dst = Bs + wave * 1024;

  f32x4 acc[4][4] = {};

  for (int k0 = kb; k0 < ke; k0 += 32) {
    __syncthreads();
    async_cp16(ap + k0,           as_dst);
    async_cp16(ap + 16 * K + k0,  as_dst + 512);
    async_cp16(bp + k0,           bs_dst);
    async_cp16(bp + 16 * K + k0,  bs_dst + 512);
    __syncthreads();
    bf16x8 af[4], bf[4];
#pragma unroll
    for (int mt = 0; mt < 4; ++mt)
      af[mt] = *reinterpret_cast<const bf16x8*>(&As[(wm * 64 + mt * 16 + col) * 32 + quad * 8]);
#pragma unroll
    for (int nt = 0; nt < 4; ++nt)
      bf[nt] = *reinterpret_cast<const bf16x8*>(&Bs[(wn * 64 + nt * 16 + col) * 32 + quad * 8]);
#pragma unroll
    for (int mt = 0; mt < 4; ++mt)
#pragma unroll
      for (int nt = 0; nt < 4; ++nt)
        acc[mt][nt] = __builtin_amdgcn_mfma_f32_16x16x32_bf16(af[mt], bf[nt], acc[mt][nt], 0, 0, 0);
  }

#pragma unroll
  for (int mt = 0; mt < 4; ++mt) {
#pragma unroll
    for (int r = 0; r < 4; ++r) {
      const int grow = bm * 128 + wm * 64 + mt * 16 + quad * 4 + r;
#pragma unroll
      for (int nt = 0; nt < 4; ++nt) {
        const int gcol = bn * 128 + wn * 64 + nt * 16 + col;
        if constexpr (MODE == 0) {
          outb[(size_t)grow * N + gcol] = f2bf(gelu_f(acc[mt][nt][r] + bias[gcol]));
        } else if constexpr (MODE == 1) {
          atomicAdd(&outf[(size_t)grow * N + gcol], acc[mt][nt][r]);
        } else {
          const float val = acc[mt][nt][r] + bias[gcol];
          const int which = gcol >> 10, c = gcol & 1023;
          const int hh = c >> 6, dd = c & 63;
          const int bb = grow >> 11, tt = grow & 2047;
          if (which == 0)
            qo[((bb * H_ + hh) * (size_t)T_ + tt) * HD_ + dd] = f2bf(val * 0.125f);
          else if (which == 1)
            ko[((bb * H_ + hh) * (size_t)T_ + tt) * HD_ + dd] = f2bf(val);
          else
            vto[((bb * H_ + hh) * (size_t)HD_ + dd) * T_ + tt] = f2bf(val);
        }
      }
    }
  }
}

// ---------------- flash attention (causal), bf16 MFMA, no-max online softmax ----------------
// grid: (B*H, T/128), qt reversed (heavy blocks first); block 256 = 4 waves, each wave
// owns 32 q rows. 64-key chunks. Row-sum via ones-MFMA (exp-safe: q pre-scaled 1/8).
#define PSTR 68
__global__ __launch_bounds__(256, 2) void attn_kernel(
    const u16* __restrict__ q, const u16* __restrict__ k,
    const u16* __restrict__ vt, u16* __restrict__ y) {
  const int bh  = blockIdx.x;
  const int qt  = (T_ / 128 - 1) - blockIdx.y;
  const int tid = threadIdx.x;
  const int wave = tid >> 6, lane = tid & 63;
  const int col = lane & 15, quad = lane >> 4;
  const int b = bh >> 4, h = bh & 15;
  const int r0w = qt * 128 + wave * 32;

  __shared__ __align__(16) u16 Klds[64 * PSTR];
  __shared__ __align__(16) u16 Vtlds[64 * PSTR];
  __shared__ __align__(16) u16 Plds[4 * 32 * PSTR];

  bf16x8 aq[2][2];
#pragma unroll
  for (int i = 0; i < 2; ++i)
#pragma unroll
    for (int j = 0; j < 2; ++j)
      aq[i][j] = *reinterpret_cast<const bf16x8*>(
          &q[((size_t)bh * T_ + r0w + i * 16 + col) * HD_ + j * 32 + quad * 8]);

  bf16x8 ones;
#pragma unroll
  for (int jj = 0; jj < 8; ++jj) ones[jj] = (__bf16)1.0f;

  f32x4 o[2][4] = {};
  f32x4 l_acc[2] = {};

  const int srow = tid >> 3, spart = tid & 7;
  u16* pw = Plds + wave * 32 * PSTR;

  for (int kb = 0; kb <= qt * 128 + 64; kb += 64) {
    __syncthreads();
    *reinterpret_cast<uint4*>(&Klds[srow * PSTR + spart * 8]) =
        *reinterpret_cast<const uint4*>(&k[((size_t)bh * T_ + kb + srow) * HD_ + spart * 8]);
    *reinterpret_cast<uint4*>(&Klds[(srow + 32) * PSTR + spart * 8]) =
        *reinterpret_cast<const uint4*>(&k[((size_t)bh * T_ + kb + srow + 32) * HD_ + spart * 8]);
    *reinterpret_cast<uint4*>(&Vtlds[srow * PSTR + spart * 8]) =
        *reinterpret_cast<const uint4*>(&vt[((size_t)bh * HD_ + srow) * T_ + kb + spart * 8]);
    *reinterpret_cast<uint4*>(&Vtlds[(srow + 32) * PSTR + spart * 8]) =
        *reinterpret_cast<const uint4*>(&vt[((size_t)bh * HD_ + srow + 32) * T_ + kb + spart * 8]);
    __syncthreads();

    if (kb > r0w + 31) continue;  // fully masked for this wave

    f32x4 s[2][4];
#pragma unroll
    for (int n = 0; n < 4; ++n) {
      const bf16x8 bk0 = *reinterpret_cast<const bf16x8*>(&Klds[(n * 16 + col) * PSTR + quad * 8]);
      const bf16x8 bk1 = *reinterpret_cast<const bf16x8*>(&Klds[(n * 16 + col) * PSTR + 32 + quad * 8]);
#pragma unroll
      for (int i = 0; i < 2; ++i) {
        f32x4 z = {};
        z = __builtin_amdgcn_mfma_f32_16x16x32_bf16(aq[i][0], bk0, z, 0, 0, 0);
        s[i][n] = __builtin_amdgcn_mfma_f32_16x16x32_bf16(aq[i][1], bk1, z, 0, 0, 0);
      }
    }

    const bool domask = (kb + 63 > r0w);
#pragma unroll
    for (int i = 0; i < 2; ++i) {
#pragma unroll
      for (int n = 0; n < 4; ++n) {
#pragma unroll
        for (int r = 0; r < 4; ++r) {
          float sv = s[i][n][r];
          if (domask) {
            const int key = kb + n * 16 + col;
            const int row = r0w + i * 16 + quad * 4 + r;
            sv = (key <= row) ? sv : -1e30f;
          }
          pw[(i * 16 + quad * 4 + r) * PSTR + n * 16 + col] = f2bf(__expf(sv));
        }
      }
    }
    __builtin_amdgcn_s_waitcnt(0xC07F);  // lgkmcnt(0): own-wave P writes visible

    bf16x8 ap0[2], ap1[2];
#pragma unroll
    for (int i = 0; i < 2; ++i) {
      ap0[i] = *reinterpret_cast<const bf16x8*>(&pw[(i * 16 + col) * PSTR + quad * 8]);
      ap1[i] = *reinterpret_cast<const bf16x8*>(&pw[(i * 16 + col) * PSTR + 32 + quad * 8]);
      l_acc[i] = __builtin_amdgcn_mfma_f32_16x16x32_bf16(ap0[i], ones, l_acc[i], 0, 0, 0);
      l_acc[i] = __builtin_amdgcn_mfma_f32_16x16x32_bf16(ap1[i], ones, l_acc[i], 0, 0, 0);
    }
#pragma unroll
    for (int n = 0; n < 4; ++n) {
      const bf16x8 bv0 = *reinterpret_cast<const bf16x8*>(&Vtlds[(n * 16 + col) * PSTR + quad * 8]);
      const bf16x8 bv1 = *reinterpret_cast<const bf16x8*>(&Vtlds[(n * 16 + col) * PSTR + 32 + quad * 8]);
#pragma unroll
      for (int i = 0; i < 2; ++i) {
        o[i][n] = __builtin_amdgcn_mfma_f32_16x16x32_bf16(ap0[i], bv0, o[i][n], 0, 0, 0);
        o[i][n] = __builtin_amdgcn_mfma_f32_16x16x32_bf16(ap1[i], bv1, o[i][n], 0, 0, 0);
      }
    }
  }

#pragma unroll
  for (int i = 0; i < 2; ++i) {
#pragma unroll
    for (int r = 0; r < 4; ++r) {
      const int qrow = r0w + i * 16 + quad * 4 + r;
      const float inv = 1.0f / l_acc[i][r];
#pragma unroll
      for (int n = 0; n < 4; ++n)
        y[((size_t)b * T_ + qrow) * C_ + h * HD_ + n * 16 + col] = f2bf(o[i][n][r] * inv);
    }
  }
}

extern "C" void kernel_launch(void* const* d_in, const int* in_sizes, int n_in,
                              void* d_out, int out_size, void* d_ws, size_t ws_size,
                              hipStream_t stream) {
  const float* x      = (const float*)d_in[0];
  const float* ln1_g  = (const float*)d_in[1];
  const float* ln1_b  = (const float*)d_in[2];
  const float* W_attn = (const float*)d_in[3];
  const float* b_attn = (const float*)d_in[4];
  const float* W_proj = (const float*)d_in[5];
  const float* b_proj = (const float*)d_in[6];
  const float* ln2_g  = (const float*)d_in[7];
  const float* ln2_b  = (const float*)d_in[8];
  const float* W_fc   = (const float*)d_in[9];
  const float* b_fc   = (const float*)d_in[10];
  const float* W_fc2  = (const float*)d_in[11];
  const float* b_fc2  = (const float*)d_in[12];
  float* out = (float*)d_out;

  char* p = (char*)d_ws;
  auto alloc = [&](size_t bytes) {
    char* r = p;
    p += (bytes + 255) & ~(size_t)255;
    return r;
  };
  u16*   h1      = (u16*)alloc((size_t)M_TOT * C_ * 2);
  u16*   wt_attn = (u16*)alloc((size_t)3 * C_ * C_ * 2);
  u16*   wt_proj = (u16*)alloc((size_t)C_ * C_ * 2);
  u16*   wt_fc   = (u16*)alloc((size_t)4 * C_ * C_ * 2);
  u16*   wt_fc2  = (u16*)alloc((size_t)C_ * 4 * C_ * 2);
  u16*   qbuf    = (u16*)alloc((size_t)M_TOT * C_ * 2);
  u16*   kbuf    = (u16*)alloc((size_t)M_TOT * C_ * 2);
  u16*   vtbuf   = (u16*)alloc((size_t)M_TOT * C_ * 2);
  u16*   ybuf    = (u16*)alloc((size_t)M_TOT * C_ * 2);
  float* x2      = (float*)alloc((size_t)M_TOT * C_ * 4);
  u16*   h2      = (u16*)alloc((size_t)M_TOT * C_ * 2);
  u16*   act     = (u16*)alloc((size_t)M_TOT * 4 * C_ * 2);

  // weights: fp32 [K][N] -> bf16 [N][K]
  transpose_bf16_kernel<<<dim3(96, 32),  256, 0, stream>>>(W_attn, wt_attn, 1024, 3072);
  transpose_bf16_kernel<<<dim3(32, 32),  256, 0, stream>>>(W_proj, wt_proj, 1024, 1024);
  transpose_bf16_kernel<<<dim3(128, 32), 256, 0, stream>>>(W_fc,   wt_fc,   1024, 4096);
  transpose_bf16_kernel<<<dim3(32, 128), 256, 0, stream>>>(W_fc2,  wt_fc2,  4096, 1024);

  // ln1
  ln_bf16_kernel<<<M_TOT, 256, 0, stream>>>(x, ln1_g, ln1_b, h1);

  // qkv = h1 @ W_attn + b_attn -> q(scaled)/k/vt
  gemm_kernel<3><<<dim3(24, 32), 256, 0, stream>>>(h1, wt_attn, b_attn,
                                                   nullptr, nullptr, qbuf, kbuf, vtbuf,
                                                   4096, 3072, 1024, 1024);
  // causal flash attention -> y [B,T,C]
  attn_kernel<<<dim3(32, 16), 256, 0, stream>>>(qbuf, kbuf, vtbuf, ybuf);

  // x2 = x + b_proj + y @ W_proj   (seed, then split-K x2 atomic partials)
  init_bias_resid_kernel<<<M_TOT, 256, 0, stream>>>(x, b_proj, x2, C_ / 4);
  gemm_kernel<1><<<dim3(8, 32, 2), 256, 0, stream>>>(ybuf, wt_proj, nullptr,
                                                     x2, nullptr, nullptr, nullptr, nullptr,
                                                     4096, 1024, 1024, 512);
  // ln2
  ln_bf16_kernel<<<M_TOT, 256, 0, stream>>>(x2, ln2_g, ln2_b, h2);

  // act = gelu(h2 @ W_fc + b_fc)
  gemm_kernel<0><<<dim3(32, 32), 256, 0, stream>>>(h2, wt_fc, b_fc,
                                                   nullptr, act, nullptr, nullptr, nullptr,
                                                   4096, 4096, 1024, 1024);
  // out = x2 + b_fc2 + act @ W_fc2   (seed, then split-K x4 atomic partials)
  init_bias_resid_kernel<<<M_TOT, 256, 0, stream>>>(x2, b_fc2, out, C_ / 4);
  gemm_kernel<1><<<dim3(8, 32, 4), 256, 0, stream>>>(act, wt_fc2, nullptr,
                                                     out, nullptr, nullptr, nullptr, nullptr,
                                                     4096, 1024, 4096, 1024);
}

// Round 4
// 385.568 us; speedup vs baseline: 1.1307x; 1.1307x over previous
//
#include <hip/hip_runtime.h>
#include <hip/hip_bf16.h>
#include <cstdint>
#include <cstddef>

// Transformer block: B=2, T=2048, C=1024, H=16, HD=64.
// bf16 MFMA for all GEMM-shaped compute; fp32 for LN stats / softmax sums / residuals.
// R4: revert split-K (atomics round-tripped 64MB to HBM, regressed). For the
// N=1024 GEMMs (proj, fc2) use a 64x128 tile -> 512 blocks = 2 independent
// blocks/CU so barrier drains overlap across blocks (m114 mechanism).
#define B_  2
#define T_  2048
#define C_  1024
#define H_  16
#define HD_ 64
#define M_TOT 4096   // B*T

typedef __bf16 bf16x8 __attribute__((ext_vector_type(8)));
typedef float  f32x4  __attribute__((ext_vector_type(4)));
typedef unsigned short u16;

__device__ __forceinline__ u16 f2bf(float f) {
  __hip_bfloat16 h = __float2bfloat16(f);
  return __builtin_bit_cast(u16, h);
}

// async global->LDS, 16B per lane; LDS dest is wave-uniform base + lane*16.
__device__ __forceinline__ void async_cp16(const u16* g, u16* l) {
  __builtin_amdgcn_global_load_lds(
      (const __attribute__((address_space(1))) void*)g,
      (__attribute__((address_space(3))) void*)l, 16, 0, 0);
}

// gelu_tanh: 0.5*x*(1+tanh z) == x * sigmoid(2z); overflow-safe via negative exp.
__device__ __forceinline__ float gelu_f(float x) {
  const float z = 0.7978845608028654f * (x + 0.044715f * x * x * x);
  return x / (1.0f + __expf(-2.0f * z));
}

// ---------------- LayerNorm (fp32 in -> bf16 out), one block per row ----------------
__global__ __launch_bounds__(256) void ln_bf16_kernel(
    const float* __restrict__ x, const float* __restrict__ g,
    const float* __restrict__ b, u16* __restrict__ out) {
  const int row = blockIdx.x;
  const int tid = threadIdx.x;
  const float4 v = reinterpret_cast<const float4*>(x)[row * 256 + tid];
  float s  = v.x + v.y + v.z + v.w;
  float sq = v.x * v.x + v.y * v.y + v.z * v.z + v.w * v.w;
#pragma unroll
  for (int off = 32; off > 0; off >>= 1) {
    s  += __shfl_xor(s, off);
    sq += __shfl_xor(sq, off);
  }
  __shared__ float red[8];
  const int wave = tid >> 6;
  if ((tid & 63) == 0) { red[wave] = s; red[4 + wave] = sq; }
  __syncthreads();
  s  = red[0] + red[1] + red[2] + red[3];
  sq = red[4] + red[5] + red[6] + red[7];
  const float mu   = s * (1.0f / 1024.0f);
  const float rstd = rsqrtf(sq * (1.0f / 1024.0f) - mu * mu + 1e-5f);
  const float4 gv = reinterpret_cast<const float4*>(g)[tid];
  const float4 bv = reinterpret_cast<const float4*>(b)[tid];
  ushort4 o;
  o.x = f2bf((v.x - mu) * rstd * gv.x + bv.x);
  o.y = f2bf((v.y - mu) * rstd * gv.y + bv.y);
  o.z = f2bf((v.z - mu) * rstd * gv.z + bv.z);
  o.w = f2bf((v.w - mu) * rstd * gv.w + bv.w);
  reinterpret_cast<ushort4*>(out)[row * 256 + tid] = o;
}

// ---------------- W[K][N] fp32 -> Wt[N][K] bf16 (tiled transpose+convert) ----------------
__global__ __launch_bounds__(256) void transpose_bf16_kernel(
    const float* __restrict__ W, u16* __restrict__ Wt, int K, int N) {
  __shared__ float tile[32][33];
  const int n0 = blockIdx.x * 32, k0 = blockIdx.y * 32;
  const int tx = threadIdx.x & 31;
  const int ty = threadIdx.x >> 5;  // 0..7
#pragma unroll
  for (int i = 0; i < 4; ++i)
    tile[ty + 8 * i][tx] = W[(k0 + ty + 8 * i) * (size_t)N + n0 + tx];
  __syncthreads();
#pragma unroll
  for (int i = 0; i < 4; ++i)
    Wt[(n0 + ty + 8 * i) * (size_t)K + k0 + tx] = f2bf(tile[tx][ty + 8 * i]);
}

// ---------------- bf16 MFMA GEMM: C[M,N] = A[M,K] @ Bt[N,K]^T, fused epilogues -------------
// Tile: BM x 128 (BM = 128 or 64). BM=64 doubles the grid for narrow-N shapes.
// MODE 0: +bias, gelu -> bf16 out                      (fc)
// MODE 1: +bias, +resid(fp32) -> fp32                  (proj, fc2)
// MODE 3: +bias, scatter q(scaled)/k [B,H,T,HD], v transposed [B,H,HD,T]  (qkv)
template <int MODE, int BM>
__global__ __launch_bounds__(256, 2) void gemm_kernel(
    const u16* __restrict__ A, const u16* __restrict__ Bt,
    const float* __restrict__ bias, const float* __restrict__ resid,
    float* __restrict__ outf, u16* __restrict__ outb,
    u16* __restrict__ qo, u16* __restrict__ ko, u16* __restrict__ vto,
    int M, int N, int K) {
  constexpr int MT = BM / 32;            // m-tiles of 16 per wave
  __shared__ __align__(16) u16 As[BM * 32];
  __shared__ __align__(16) u16 Bs[128 * 32];
  const int tid  = threadIdx.x;
  const int wave = tid >> 6, lane = tid & 63;
  const int col  = lane & 15, quad = lane >> 4;
  const int wm   = wave >> 1, wn = wave & 1;
  const int bn = blockIdx.x, bm = blockIdx.y;

  const int ar = bm * BM + wave * (BM / 4) + (lane >> 2);
  const int br = bn * 128 + wave * 32 + (lane >> 2);
  const int kc = (lane & 3) * 8;
  const u16* ap = A  + (size_t)ar * K + kc;
  const u16* bp = Bt + (size_t)br * K + kc;
  u16* as_dst = As + wave * (BM / 4) * 32;
  u16* bs_dst = Bs + wave * 1024;

  f32x4 acc[MT][4] = {};

  for (int k0 = 0; k0 < K; k0 += 32) {
    __syncthreads();
    async_cp16(ap + k0, as_dst);
    if constexpr (BM == 128) async_cp16(ap + 16 * K + k0, as_dst + 512);
    async_cp16(bp + k0,          bs_dst);
    async_cp16(bp + 16 * K + k0, bs_dst + 512);
    __syncthreads();
    bf16x8 af[MT], bf[4];
#pragma unroll
    for (int mt = 0; mt < MT; ++mt)
      af[mt] = *reinterpret_cast<const bf16x8*>(&As[(wm * (BM / 2) + mt * 16 + col) * 32 + quad * 8]);
#pragma unroll
    for (int nt = 0; nt < 4; ++nt)
      bf[nt] = *reinterpret_cast<const bf16x8*>(&Bs[(wn * 64 + nt * 16 + col) * 32 + quad * 8]);
#pragma unroll
    for (int mt = 0; mt < MT; ++mt)
#pragma unroll
      for (int nt = 0; nt < 4; ++nt)
        acc[mt][nt] = __builtin_amdgcn_mfma_f32_16x16x32_bf16(af[mt], bf[nt], acc[mt][nt], 0, 0, 0);
  }

#pragma unroll
  for (int mt = 0; mt < MT; ++mt) {
#pragma unroll
    for (int r = 0; r < 4; ++r) {
      const int grow = bm * BM + wm * (BM / 2) + mt * 16 + quad * 4 + r;
#pragma unroll
      for (int nt = 0; nt < 4; ++nt) {
        const int gcol = bn * 128 + wn * 64 + nt * 16 + col;
        const float val = acc[mt][nt][r] + bias[gcol];
        if constexpr (MODE == 0) {
          outb[(size_t)grow * N + gcol] = f2bf(gelu_f(val));
        } else if constexpr (MODE == 1) {
          outf[(size_t)grow * N + gcol] = resid[(size_t)grow * N + gcol] + val;
        } else {
          const int which = gcol >> 10, c = gcol & 1023;
          const int hh = c >> 6, dd = c & 63;
          const int bb = grow >> 11, tt = grow & 2047;
          if (which == 0)
            qo[((bb * H_ + hh) * (size_t)T_ + tt) * HD_ + dd] = f2bf(val * 0.125f);
          else if (which == 1)
            ko[((bb * H_ + hh) * (size_t)T_ + tt) * HD_ + dd] = f2bf(val);
          else
            vto[((bb * H_ + hh) * (size_t)HD_ + dd) * T_ + tt] = f2bf(val);
        }
      }
    }
  }
}

// ---------------- flash attention (causal), bf16 MFMA, no-max online softmax ----------------
// grid: (B*H, T/128), qt reversed (heavy blocks first); block 256 = 4 waves, each wave
// owns 32 q rows. 64-key chunks. Row-sum via ones-MFMA (exp-safe: q pre-scaled 1/8).
#define PSTR 68
__global__ __launch_bounds__(256, 2) void attn_kernel(
    const u16* __restrict__ q, const u16* __restrict__ k,
    const u16* __restrict__ vt, u16* __restrict__ y) {
  const int bh  = blockIdx.x;
  const int qt  = (T_ / 128 - 1) - blockIdx.y;
  const int tid = threadIdx.x;
  const int wave = tid >> 6, lane = tid & 63;
  const int col = lane & 15, quad = lane >> 4;
  const int b = bh >> 4, h = bh & 15;
  const int r0w = qt * 128 + wave * 32;

  __shared__ __align__(16) u16 Klds[64 * PSTR];
  __shared__ __align__(16) u16 Vtlds[64 * PSTR];
  __shared__ __align__(16) u16 Plds[4 * 32 * PSTR];

  bf16x8 aq[2][2];
#pragma unroll
  for (int i = 0; i < 2; ++i)
#pragma unroll
    for (int j = 0; j < 2; ++j)
      aq[i][j] = *reinterpret_cast<const bf16x8*>(
          &q[((size_t)bh * T_ + r0w + i * 16 + col) * HD_ + j * 32 + quad * 8]);

  bf16x8 ones;
#pragma unroll
  for (int jj = 0; jj < 8; ++jj) ones[jj] = (__bf16)1.0f;

  f32x4 o[2][4] = {};
  f32x4 l_acc[2] = {};

  const int srow = tid >> 3, spart = tid & 7;
  u16* pw = Plds + wave * 32 * PSTR;

  for (int kb = 0; kb <= qt * 128 + 64; kb += 64) {
    __syncthreads();
    *reinterpret_cast<uint4*>(&Klds[srow * PSTR + spart * 8]) =
        *reinterpret_cast<const uint4*>(&k[((size_t)bh * T_ + kb + srow) * HD_ + spart * 8]);
    *reinterpret_cast<uint4*>(&Klds[(srow + 32) * PSTR + spart * 8]) =
        *reinterpret_cast<const uint4*>(&k[((size_t)bh * T_ + kb + srow + 32) * HD_ + spart * 8]);
    *reinterpret_cast<uint4*>(&Vtlds[srow * PSTR + spart * 8]) =
        *reinterpret_cast<const uint4*>(&vt[((size_t)bh * HD_ + srow) * T_ + kb + spart * 8]);
    *reinterpret_cast<uint4*>(&Vtlds[(srow + 32) * PSTR + spart * 8]) =
        *reinterpret_cast<const uint4*>(&vt[((size_t)bh * HD_ + srow + 32) * T_ + kb + spart * 8]);
    __syncthreads();

    if (kb > r0w + 31) continue;  // fully masked for this wave

    f32x4 s[2][4];
#pragma unroll
    for (int n = 0; n < 4; ++n) {
      const bf16x8 bk0 = *reinterpret_cast<const bf16x8*>(&Klds[(n * 16 + col) * PSTR + quad * 8]);
      const bf16x8 bk1 = *reinterpret_cast<const bf16x8*>(&Klds[(n * 16 + col) * PSTR + 32 + quad * 8]);
#pragma unroll
      for (int i = 0; i < 2; ++i) {
        f32x4 z = {};
        z = __builtin_amdgcn_mfma_f32_16x16x32_bf16(aq[i][0], bk0, z, 0, 0, 0);
        s[i][n] = __builtin_amdgcn_mfma_f32_16x16x32_bf16(aq[i][1], bk1, z, 0, 0, 0);
      }
    }

    const bool domask = (kb + 63 > r0w);
#pragma unroll
    for (int i = 0; i < 2; ++i) {
#pragma unroll
      for (int n = 0; n < 4; ++n) {
#pragma unroll
        for (int r = 0; r < 4; ++r) {
          float sv = s[i][n][r];
          if (domask) {
            const int key = kb + n * 16 + col;
            const int row = r0w + i * 16 + quad * 4 + r;
            sv = (key <= row) ? sv : -1e30f;
          }
          pw[(i * 16 + quad * 4 + r) * PSTR + n * 16 + col] = f2bf(__expf(sv));
        }
      }
    }
    __builtin_amdgcn_s_waitcnt(0xC07F);  // lgkmcnt(0): own-wave P writes visible

    bf16x8 ap0[2], ap1[2];
#pragma unroll
    for (int i = 0; i < 2; ++i) {
      ap0[i] = *reinterpret_cast<const bf16x8*>(&pw[(i * 16 + col) * PSTR + quad * 8]);
      ap1[i] = *reinterpret_cast<const bf16x8*>(&pw[(i * 16 + col) * PSTR + 32 + quad * 8]);
      l_acc[i] = __builtin_amdgcn_mfma_f32_16x16x32_bf16(ap0[i], ones, l_acc[i], 0, 0, 0);
      l_acc[i] = __builtin_amdgcn_mfma_f32_16x16x32_bf16(ap1[i], ones, l_acc[i], 0, 0, 0);
    }
#pragma unroll
    for (int n = 0; n < 4; ++n) {
      const bf16x8 bv0 = *reinterpret_cast<const bf16x8*>(&Vtlds[(n * 16 + col) * PSTR + quad * 8]);
      const bf16x8 bv1 = *reinterpret_cast<const bf16x8*>(&Vtlds[(n * 16 + col) * PSTR + 32 + quad * 8]);
#pragma unroll
      for (int i = 0; i < 2; ++i) {
        o[i][n] = __builtin_amdgcn_mfma_f32_16x16x32_bf16(ap0[i], bv0, o[i][n], 0, 0, 0);
        o[i][n] = __builtin_amdgcn_mfma_f32_16x16x32_bf16(ap1[i], bv1, o[i][n], 0, 0, 0);
      }
    }
  }

#pragma unroll
  for (int i = 0; i < 2; ++i) {
#pragma unroll
    for (int r = 0; r < 4; ++r) {
      const int qrow = r0w + i * 16 + quad * 4 + r;
      const float inv = 1.0f / l_acc[i][r];
#pragma unroll
      for (int n = 0; n < 4; ++n)
        y[((size_t)b * T_ + qrow) * C_ + h * HD_ + n * 16 + col] = f2bf(o[i][n][r] * inv);
    }
  }
}

extern "C" void kernel_launch(void* const* d_in, const int* in_sizes, int n_in,
                              void* d_out, int out_size, void* d_ws, size_t ws_size,
                              hipStream_t stream) {
  const float* x      = (const float*)d_in[0];
  const float* ln1_g  = (const float*)d_in[1];
  const float* ln1_b  = (const float*)d_in[2];
  const float* W_attn = (const float*)d_in[3];
  const float* b_attn = (const float*)d_in[4];
  const float* W_proj = (const float*)d_in[5];
  const float* b_proj = (const float*)d_in[6];
  const float* ln2_g  = (const float*)d_in[7];
  const float* ln2_b  = (const float*)d_in[8];
  const float* W_fc   = (const float*)d_in[9];
  const float* b_fc   = (const float*)d_in[10];
  const float* W_fc2  = (const float*)d_in[11];
  const float* b_fc2  = (const float*)d_in[12];
  float* out = (float*)d_out;

  char* p = (char*)d_ws;
  auto alloc = [&](size_t bytes) {
    char* r = p;
    p += (bytes + 255) & ~(size_t)255;
    return r;
  };
  u16*   h1      = (u16*)alloc((size_t)M_TOT * C_ * 2);
  u16*   wt_attn = (u16*)alloc((size_t)3 * C_ * C_ * 2);
  u16*   wt_proj = (u16*)alloc((size_t)C_ * C_ * 2);
  u16*   wt_fc   = (u16*)alloc((size_t)4 * C_ * C_ * 2);
  u16*   wt_fc2  = (u16*)alloc((size_t)C_ * 4 * C_ * 2);
  u16*   qbuf    = (u16*)alloc((size_t)M_TOT * C_ * 2);
  u16*   kbuf    = (u16*)alloc((size_t)M_TOT * C_ * 2);
  u16*   vtbuf   = (u16*)alloc((size_t)M_TOT * C_ * 2);
  u16*   ybuf    = (u16*)alloc((size_t)M_TOT * C_ * 2);
  float* x2      = (float*)alloc((size_t)M_TOT * C_ * 4);
  u16*   h2      = (u16*)alloc((size_t)M_TOT * C_ * 2);
  u16*   act     = (u16*)alloc((size_t)M_TOT * 4 * C_ * 2);

  // weights: fp32 [K][N] -> bf16 [N][K]
  transpose_bf16_kernel<<<dim3(96, 32),  256, 0, stream>>>(W_attn, wt_attn, 1024, 3072);
  transpose_bf16_kernel<<<dim3(32, 32),  256, 0, stream>>>(W_proj, wt_proj, 1024, 1024);
  transpose_bf16_kernel<<<dim3(128, 32), 256, 0, stream>>>(W_fc,   wt_fc,   1024, 4096);
  transpose_bf16_kernel<<<dim3(32, 128), 256, 0, stream>>>(W_fc2,  wt_fc2,  4096, 1024);

  // ln1
  ln_bf16_kernel<<<M_TOT, 256, 0, stream>>>(x, ln1_g, ln1_b, h1);

  // qkv = h1 @ W_attn + b_attn -> q(scaled)/k/vt    (768 blocks = 3/CU)
  gemm_kernel<3, 128><<<dim3(24, 32), 256, 0, stream>>>(h1, wt_attn, b_attn, nullptr,
                                                        nullptr, nullptr, qbuf, kbuf, vtbuf,
                                                        4096, 3072, 1024);
  // causal flash attention -> y [B,T,C]
  attn_kernel<<<dim3(32, 16), 256, 0, stream>>>(qbuf, kbuf, vtbuf, ybuf);

  // x2 = x + y @ W_proj + b_proj    (64x128 tile -> 512 blocks = 2/CU)
  gemm_kernel<1, 64><<<dim3(8, 64), 256, 0, stream>>>(ybuf, wt_proj, b_proj, x,
                                                      x2, nullptr, nullptr, nullptr, nullptr,
                                                      4096, 1024, 1024);
  // ln2
  ln_bf16_kernel<<<M_TOT, 256, 0, stream>>>(x2, ln2_g, ln2_b, h2);

  // act = gelu(h2 @ W_fc + b_fc)    (1024 blocks = 4/CU)
  gemm_kernel<0, 128><<<dim3(32, 32), 256, 0, stream>>>(h2, wt_fc, b_fc, nullptr,
                                                        nullptr, act, nullptr, nullptr, nullptr,
                                                        4096, 4096, 1024);
  // out = x2 + act @ W_fc2 + b_fc2  (64x128 tile -> 512 blocks = 2/CU)
  gemm_kernel<1, 64><<<dim3(8, 64), 256, 0, stream>>>(act, wt_fc2, b_fc2, x2,
                                                      out, nullptr, nullptr, nullptr, nullptr,
                                                      4096, 1024, 4096);
}

// Round 5
// 369.896 us; speedup vs baseline: 1.1786x; 1.0424x over previous
//
#include <hip/hip_runtime.h>
#include <hip/hip_bf16.h>
#include <cstdint>
#include <cstddef>

// Transformer block: B=2, T=2048, C=1024, H=16, HD=64.
// bf16 MFMA for all GEMM-shaped compute; fp32 for LN stats / softmax sums / residuals.
// R5: attention restructured — 64-row q-tiles (1024 blocks, 4+/CU resident),
// software-pipelined K/V staging (global loads for chunk c+1 in flight during
// chunk c's compute). GEMMs unchanged from R4 (proj/fc2 use 64x128 tiles).
#define B_  2
#define T_  2048
#define C_  1024
#define H_  16
#define HD_ 64
#define M_TOT 4096   // B*T

typedef __bf16 bf16x8 __attribute__((ext_vector_type(8)));
typedef float  f32x4  __attribute__((ext_vector_type(4)));
typedef unsigned short u16;

__device__ __forceinline__ u16 f2bf(float f) {
  __hip_bfloat16 h = __float2bfloat16(f);
  return __builtin_bit_cast(u16, h);
}

// async global->LDS, 16B per lane; LDS dest is wave-uniform base + lane*16.
__device__ __forceinline__ void async_cp16(const u16* g, u16* l) {
  __builtin_amdgcn_global_load_lds(
      (const __attribute__((address_space(1))) void*)g,
      (__attribute__((address_space(3))) void*)l, 16, 0, 0);
}

// gelu_tanh: 0.5*x*(1+tanh z) == x * sigmoid(2z); overflow-safe via negative exp.
__device__ __forceinline__ float gelu_f(float x) {
  const float z = 0.7978845608028654f * (x + 0.044715f * x * x * x);
  return x / (1.0f + __expf(-2.0f * z));
}

// ---------------- LayerNorm (fp32 in -> bf16 out), one block per row ----------------
__global__ __launch_bounds__(256) void ln_bf16_kernel(
    const float* __restrict__ x, const float* __restrict__ g,
    const float* __restrict__ b, u16* __restrict__ out) {
  const int row = blockIdx.x;
  const int tid = threadIdx.x;
  const float4 v = reinterpret_cast<const float4*>(x)[row * 256 + tid];
  float s  = v.x + v.y + v.z + v.w;
  float sq = v.x * v.x + v.y * v.y + v.z * v.z + v.w * v.w;
#pragma unroll
  for (int off = 32; off > 0; off >>= 1) {
    s  += __shfl_xor(s, off);
    sq += __shfl_xor(sq, off);
  }
  __shared__ float red[8];
  const int wave = tid >> 6;
  if ((tid & 63) == 0) { red[wave] = s; red[4 + wave] = sq; }
  __syncthreads();
  s  = red[0] + red[1] + red[2] + red[3];
  sq = red[4] + red[5] + red[6] + red[7];
  const float mu   = s * (1.0f / 1024.0f);
  const float rstd = rsqrtf(sq * (1.0f / 1024.0f) - mu * mu + 1e-5f);
  const float4 gv = reinterpret_cast<const float4*>(g)[tid];
  const float4 bv = reinterpret_cast<const float4*>(b)[tid];
  ushort4 o;
  o.x = f2bf((v.x - mu) * rstd * gv.x + bv.x);
  o.y = f2bf((v.y - mu) * rstd * gv.y + bv.y);
  o.z = f2bf((v.z - mu) * rstd * gv.z + bv.z);
  o.w = f2bf((v.w - mu) * rstd * gv.w + bv.w);
  reinterpret_cast<ushort4*>(out)[row * 256 + tid] = o;
}

// ---------------- W[K][N] fp32 -> Wt[N][K] bf16 (tiled transpose+convert) ----------------
__global__ __launch_bounds__(256) void transpose_bf16_kernel(
    const float* __restrict__ W, u16* __restrict__ Wt, int K, int N) {
  __shared__ float tile[32][33];
  const int n0 = blockIdx.x * 32, k0 = blockIdx.y * 32;
  const int tx = threadIdx.x & 31;
  const int ty = threadIdx.x >> 5;  // 0..7
#pragma unroll
  for (int i = 0; i < 4; ++i)
    tile[ty + 8 * i][tx] = W[(k0 + ty + 8 * i) * (size_t)N + n0 + tx];
  __syncthreads();
#pragma unroll
  for (int i = 0; i < 4; ++i)
    Wt[(n0 + ty + 8 * i) * (size_t)K + k0 + tx] = f2bf(tile[tx][ty + 8 * i]);
}

// ---------------- bf16 MFMA GEMM: C[M,N] = A[M,K] @ Bt[N,K]^T, fused epilogues -------------
// Tile: BM x 128 (BM = 128 or 64). BM=64 doubles the grid for narrow-N shapes.
// MODE 0: +bias, gelu -> bf16 out                      (fc)
// MODE 1: +bias, +resid(fp32) -> fp32                  (proj, fc2)
// MODE 3: +bias, scatter q(scaled)/k [B,H,T,HD], v transposed [B,H,HD,T]  (qkv)
template <int MODE, int BM>
__global__ __launch_bounds__(256, 2) void gemm_kernel(
    const u16* __restrict__ A, const u16* __restrict__ Bt,
    const float* __restrict__ bias, const float* __restrict__ resid,
    float* __restrict__ outf, u16* __restrict__ outb,
    u16* __restrict__ qo, u16* __restrict__ ko, u16* __restrict__ vto,
    int M, int N, int K) {
  constexpr int MT = BM / 32;            // m-tiles of 16 per wave
  __shared__ __align__(16) u16 As[BM * 32];
  __shared__ __align__(16) u16 Bs[128 * 32];
  const int tid  = threadIdx.x;
  const int wave = tid >> 6, lane = tid & 63;
  const int col  = lane & 15, quad = lane >> 4;
  const int wm   = wave >> 1, wn = wave & 1;
  const int bn = blockIdx.x, bm = blockIdx.y;

  const int ar = bm * BM + wave * (BM / 4) + (lane >> 2);
  const int br = bn * 128 + wave * 32 + (lane >> 2);
  const int kc = (lane & 3) * 8;
  const u16* ap = A  + (size_t)ar * K + kc;
  const u16* bp = Bt + (size_t)br * K + kc;
  u16* as_dst = As + wave * (BM / 4) * 32;
  u16* bs_dst = Bs + wave * 1024;

  f32x4 acc[MT][4] = {};

  for (int k0 = 0; k0 < K; k0 += 32) {
    __syncthreads();
    async_cp16(ap + k0, as_dst);
    if constexpr (BM == 128) async_cp16(ap + 16 * K + k0, as_dst + 512);
    async_cp16(bp + k0,          bs_dst);
    async_cp16(bp + 16 * K + k0, bs_dst + 512);
    __syncthreads();
    bf16x8 af[MT], bf[4];
#pragma unroll
    for (int mt = 0; mt < MT; ++mt)
      af[mt] = *reinterpret_cast<const bf16x8*>(&As[(wm * (BM / 2) + mt * 16 + col) * 32 + quad * 8]);
#pragma unroll
    for (int nt = 0; nt < 4; ++nt)
      bf[nt] = *reinterpret_cast<const bf16x8*>(&Bs[(wn * 64 + nt * 16 + col) * 32 + quad * 8]);
#pragma unroll
    for (int mt = 0; mt < MT; ++mt)
#pragma unroll
      for (int nt = 0; nt < 4; ++nt)
        acc[mt][nt] = __builtin_amdgcn_mfma_f32_16x16x32_bf16(af[mt], bf[nt], acc[mt][nt], 0, 0, 0);
  }

#pragma unroll
  for (int mt = 0; mt < MT; ++mt) {
#pragma unroll
    for (int r = 0; r < 4; ++r) {
      const int grow = bm * BM + wm * (BM / 2) + mt * 16 + quad * 4 + r;
#pragma unroll
      for (int nt = 0; nt < 4; ++nt) {
        const int gcol = bn * 128 + wn * 64 + nt * 16 + col;
        const float val = acc[mt][nt][r] + bias[gcol];
        if constexpr (MODE == 0) {
          outb[(size_t)grow * N + gcol] = f2bf(gelu_f(val));
        } else if constexpr (MODE == 1) {
          outf[(size_t)grow * N + gcol] = resid[(size_t)grow * N + gcol] + val;
        } else {
          const int which = gcol >> 10, c = gcol & 1023;
          const int hh = c >> 6, dd = c & 63;
          const int bb = grow >> 11, tt = grow & 2047;
          if (which == 0)
            qo[((bb * H_ + hh) * (size_t)T_ + tt) * HD_ + dd] = f2bf(val * 0.125f);
          else if (which == 1)
            ko[((bb * H_ + hh) * (size_t)T_ + tt) * HD_ + dd] = f2bf(val);
          else
            vto[((bb * H_ + hh) * (size_t)HD_ + dd) * T_ + tt] = f2bf(val);
        }
      }
    }
  }
}

// ---------------- flash attention (causal), bf16 MFMA, no-max online softmax ----------------
// grid: (B*H, T/64); block 256 = 4 waves, each wave owns 16 q rows. 64-key chunks,
// software-pipelined staging (next chunk's global loads fly during current compute).
// Row-sum via ones-MFMA (exp-safe: q pre-scaled 1/8). LDS rows padded to 68.
#define PSTR 68
__global__ __launch_bounds__(256, 4) void attn_kernel(
    const u16* __restrict__ q, const u16* __restrict__ k,
    const u16* __restrict__ vt, u16* __restrict__ y) {
  const int bh  = blockIdx.x;
  const int qt  = (T_ / 64 - 1) - blockIdx.y;
  const int tid = threadIdx.x;
  const int wave = tid >> 6, lane = tid & 63;
  const int col = lane & 15, quad = lane >> 4;
  const int b = bh >> 4, h = bh & 15;
  const int r0w = qt * 64 + wave * 16;   // wave's 16 q rows

  __shared__ __align__(16) u16 Klds[64 * PSTR];     // [key][d]
  __shared__ __align__(16) u16 Vtlds[64 * PSTR];    // [d][key]
  __shared__ __align__(16) u16 Plds[4 * 16 * PSTR]; // per-wave [qrow][key]

  bf16x8 aq[2];
#pragma unroll
  for (int j = 0; j < 2; ++j)
    aq[j] = *reinterpret_cast<const bf16x8*>(
        &q[((size_t)bh * T_ + r0w + col) * HD_ + j * 32 + quad * 8]);

  bf16x8 ones;
#pragma unroll
  for (int jj = 0; jj < 8; ++jj) ones[jj] = (__bf16)1.0f;

  f32x4 o[4] = {};
  f32x4 l_acc = {};

  const int srow = tid >> 3, spart = tid & 7;   // 32 rows x 8 parts
  u16* pw = Plds + wave * 16 * PSTR;
  const u16* kbase  = k  + (size_t)bh * T_ * HD_ + srow * HD_ + spart * 8;
  const u16* vtbase = vt + (size_t)bh * HD_ * T_ + srow * T_ + spart * 8;

  const int kb_last = qt * 64;

  uint4 kv0, kv1, kv2, kv3;
  // prefetch chunk 0
  kv0 = *reinterpret_cast<const uint4*>(kbase);
  kv1 = *reinterpret_cast<const uint4*>(kbase + 32 * HD_);
  kv2 = *reinterpret_cast<const uint4*>(vtbase);
  kv3 = *reinterpret_cast<const uint4*>(vtbase + 32 * T_);

  for (int kb = 0; kb <= kb_last; kb += 64) {
    // write staged regs to LDS
    *reinterpret_cast<uint4*>(&Klds[srow * PSTR + spart * 8])        = kv0;
    *reinterpret_cast<uint4*>(&Klds[(srow + 32) * PSTR + spart * 8]) = kv1;
    *reinterpret_cast<uint4*>(&Vtlds[srow * PSTR + spart * 8])        = kv2;
    *reinterpret_cast<uint4*>(&Vtlds[(srow + 32) * PSTR + spart * 8]) = kv3;
    __syncthreads();

    // issue next chunk's global loads (latency hidden behind compute below)
    if (kb < kb_last) {
      const int nk = kb + 64;
      kv0 = *reinterpret_cast<const uint4*>(kbase + (size_t)nk * HD_);
      kv1 = *reinterpret_cast<const uint4*>(kbase + (size_t)(nk + 32) * HD_ - 32 * HD_ + 32 * HD_);
      kv1 = *reinterpret_cast<const uint4*>(kbase + (size_t)nk * HD_ + 32 * HD_);
      kv2 = *reinterpret_cast<const uint4*>(vtbase + nk);
      kv3 = *reinterpret_cast<const uint4*>(vtbase + 32 * T_ + nk);
    }

    // QK^T: 16 rows x 64 keys
    f32x4 s[4];
#pragma unroll
    for (int n = 0; n < 4; ++n) {
      const bf16x8 bk0 = *reinterpret_cast<const bf16x8*>(&Klds[(n * 16 + col) * PSTR + quad * 8]);
      const bf16x8 bk1 = *reinterpret_cast<const bf16x8*>(&Klds[(n * 16 + col) * PSTR + 32 + quad * 8]);
      f32x4 z = {};
      z = __builtin_amdgcn_mfma_f32_16x16x32_bf16(aq[0], bk0, z, 0, 0, 0);
      s[n] = __builtin_amdgcn_mfma_f32_16x16x32_bf16(aq[1], bk1, z, 0, 0, 0);
    }

    // exp + causal mask (only the final/diagonal chunk needs masking); write P
    const bool domask = (kb == kb_last);
#pragma unroll
    for (int n = 0; n < 4; ++n) {
#pragma unroll
      for (int r = 0; r < 4; ++r) {
        float sv = s[n][r];
        if (domask) {
          const int key = kb + n * 16 + col;
          const int row = r0w + quad * 4 + r;
          sv = (key <= row) ? sv : -1e30f;
        }
        pw[(quad * 4 + r) * PSTR + n * 16 + col] = f2bf(__expf(sv));
      }
    }
    __builtin_amdgcn_s_waitcnt(0xC07F);  // lgkmcnt(0): own-wave P writes visible

    const bf16x8 ap0 = *reinterpret_cast<const bf16x8*>(&pw[col * PSTR + quad * 8]);
    const bf16x8 ap1 = *reinterpret_cast<const bf16x8*>(&pw[col * PSTR + 32 + quad * 8]);
    l_acc = __builtin_amdgcn_mfma_f32_16x16x32_bf16(ap0, ones, l_acc, 0, 0, 0);
    l_acc = __builtin_amdgcn_mfma_f32_16x16x32_bf16(ap1, ones, l_acc, 0, 0, 0);
#pragma unroll
    for (int n = 0; n < 4; ++n) {
      const bf16x8 bv0 = *reinterpret_cast<const bf16x8*>(&Vtlds[(n * 16 + col) * PSTR + quad * 8]);
      const bf16x8 bv1 = *reinterpret_cast<const bf16x8*>(&Vtlds[(n * 16 + col) * PSTR + 32 + quad * 8]);
      o[n] = __builtin_amdgcn_mfma_f32_16x16x32_bf16(ap0, bv0, o[n], 0, 0, 0);
      o[n] = __builtin_amdgcn_mfma_f32_16x16x32_bf16(ap1, bv1, o[n], 0, 0, 0);
    }
    __syncthreads();  // all waves done reading K/V before next chunk's ds_write
  }

#pragma unroll
  for (int r = 0; r < 4; ++r) {
    const int qrow = r0w + quad * 4 + r;
    const float inv = 1.0f / l_acc[r];
#pragma unroll
    for (int n = 0; n < 4; ++n)
      y[((size_t)b * T_ + qrow) * C_ + h * HD_ + n * 16 + col] = f2bf(o[n][r] * inv);
  }
}

extern "C" void kernel_launch(void* const* d_in, const int* in_sizes, int n_in,
                              void* d_out, int out_size, void* d_ws, size_t ws_size,
                              hipStream_t stream) {
  const float* x      = (const float*)d_in[0];
  const float* ln1_g  = (const float*)d_in[1];
  const float* ln1_b  = (const float*)d_in[2];
  const float* W_attn = (const float*)d_in[3];
  const float* b_attn = (const float*)d_in[4];
  const float* W_proj = (const float*)d_in[5];
  const float* b_proj = (const float*)d_in[6];
  const float* ln2_g  = (const float*)d_in[7];
  const float* ln2_b  = (const float*)d_in[8];
  const float* W_fc   = (const float*)d_in[9];
  const float* b_fc   = (const float*)d_in[10];
  const float* W_fc2  = (const float*)d_in[11];
  const float* b_fc2  = (const float*)d_in[12];
  float* out = (float*)d_out;

  char* p = (char*)d_ws;
  auto alloc = [&](size_t bytes) {
    char* r = p;
    p += (bytes + 255) & ~(size_t)255;
    return r;
  };
  u16*   h1      = (u16*)alloc((size_t)M_TOT * C_ * 2);
  u16*   wt_attn = (u16*)alloc((size_t)3 * C_ * C_ * 2);
  u16*   wt_proj = (u16*)alloc((size_t)C_ * C_ * 2);
  u16*   wt_fc   = (u16*)alloc((size_t)4 * C_ * C_ * 2);
  u16*   wt_fc2  = (u16*)alloc((size_t)C_ * 4 * C_ * 2);
  u16*   qbuf    = (u16*)alloc((size_t)M_TOT * C_ * 2);
  u16*   kbuf    = (u16*)alloc((size_t)M_TOT * C_ * 2);
  u16*   vtbuf   = (u16*)alloc((size_t)M_TOT * C_ * 2);
  u16*   ybuf    = (u16*)alloc((size_t)M_TOT * C_ * 2);
  float* x2      = (float*)alloc((size_t)M_TOT * C_ * 4);
  u16*   h2      = (u16*)alloc((size_t)M_TOT * C_ * 2);
  u16*   act     = (u16*)alloc((size_t)M_TOT * 4 * C_ * 2);

  // weights: fp32 [K][N] -> bf16 [N][K]
  transpose_bf16_kernel<<<dim3(96, 32),  256, 0, stream>>>(W_attn, wt_attn, 1024, 3072);
  transpose_bf16_kernel<<<dim3(32, 32),  256, 0, stream>>>(W_proj, wt_proj, 1024, 1024);
  transpose_bf16_kernel<<<dim3(128, 32), 256, 0, stream>>>(W_fc,   wt_fc,   1024, 4096);
  transpose_bf16_kernel<<<dim3(32, 128), 256, 0, stream>>>(W_fc2,  wt_fc2,  4096, 1024);

  // ln1
  ln_bf16_kernel<<<M_TOT, 256, 0, stream>>>(x, ln1_g, ln1_b, h1);

  // qkv = h1 @ W_attn + b_attn -> q(scaled)/k/vt    (768 blocks = 3/CU)
  gemm_kernel<3, 128><<<dim3(24, 32), 256, 0, stream>>>(h1, wt_attn, b_attn, nullptr,
                                                        nullptr, nullptr, qbuf, kbuf, vtbuf,
                                                        4096, 3072, 1024);
  // causal flash attention -> y [B,T,C]   (1024 blocks, 64-row q-tiles)
  attn_kernel<<<dim3(32, 32), 256, 0, stream>>>(qbuf, kbuf, vtbuf, ybuf);

  // x2 = x + y @ W_proj + b_proj    (64x128 tile -> 512 blocks = 2/CU)
  gemm_kernel<1, 64><<<dim3(8, 64), 256, 0, stream>>>(ybuf, wt_proj, b_proj, x,
                                                      x2, nullptr, nullptr, nullptr, nullptr,
                                                      4096, 1024, 1024);
  // ln2
  ln_bf16_kernel<<<M_TOT, 256, 0, stream>>>(x2, ln2_g, ln2_b, h2);

  // act = gelu(h2 @ W_fc + b_fc)    (1024 blocks = 4/CU)
  gemm_kernel<0, 128><<<dim3(32, 32), 256, 0, stream>>>(h2, wt_fc, b_fc, nullptr,
                                                        nullptr, act, nullptr, nullptr, nullptr,
                                                        4096, 4096, 1024);
  // out = x2 + act @ W_fc2 + b_fc2  (64x128 tile -> 512 blocks = 2/CU)
  gemm_kernel<1, 64><<<dim3(8, 64), 256, 0, stream>>>(act, wt_fc2, b_fc2, x2,
                                                      out, nullptr, nullptr, nullptr, nullptr,
                                                      4096, 1024, 4096);
}

// Round 6
// 338.434 us; speedup vs baseline: 1.2882x; 1.0930x over previous
//
#include <hip/hip_runtime.h>
#include <hip/hip_bf16.h>
#include <cstdint>
#include <cstddef>

// Transformer block: B=2, T=2048, C=1024, H=16, HD=64.
// bf16 MFMA for all GEMM-shaped compute; fp32 for LN stats / softmax sums / residuals.
// R6: GEMM K-loop -> BK=64 (2x MFMA per barrier), XOR-swizzled LDS (conflict-free
// 128B rows), XCD-aware block swizzle (A-tile L2 reuse). Attn unchanged from R5.
#define B_  2
#define T_  2048
#define C_  1024
#define H_  16
#define HD_ 64
#define M_TOT 4096   // B*T

typedef __bf16 bf16x8 __attribute__((ext_vector_type(8)));
typedef float  f32x4  __attribute__((ext_vector_type(4)));
typedef unsigned short u16;

__device__ __forceinline__ u16 f2bf(float f) {
  __hip_bfloat16 h = __float2bfloat16(f);
  return __builtin_bit_cast(u16, h);
}

// async global->LDS, 16B per lane; LDS dest is wave-uniform base + lane*16.
__device__ __forceinline__ void async_cp16(const u16* g, u16* l) {
  __builtin_amdgcn_global_load_lds(
      (const __attribute__((address_space(1))) void*)g,
      (__attribute__((address_space(3))) void*)l, 16, 0, 0);
}

// gelu_tanh: 0.5*x*(1+tanh z) == x * sigmoid(2z); overflow-safe via negative exp.
__device__ __forceinline__ float gelu_f(float x) {
  const float z = 0.7978845608028654f * (x + 0.044715f * x * x * x);
  return x / (1.0f + __expf(-2.0f * z));
}

// ---------------- LayerNorm (fp32 in -> bf16 out), one block per row ----------------
__global__ __launch_bounds__(256) void ln_bf16_kernel(
    const float* __restrict__ x, const float* __restrict__ g,
    const float* __restrict__ b, u16* __restrict__ out) {
  const int row = blockIdx.x;
  const int tid = threadIdx.x;
  const float4 v = reinterpret_cast<const float4*>(x)[row * 256 + tid];
  float s  = v.x + v.y + v.z + v.w;
  float sq = v.x * v.x + v.y * v.y + v.z * v.z + v.w * v.w;
#pragma unroll
  for (int off = 32; off > 0; off >>= 1) {
    s  += __shfl_xor(s, off);
    sq += __shfl_xor(sq, off);
  }
  __shared__ float red[8];
  const int wave = tid >> 6;
  if ((tid & 63) == 0) { red[wave] = s; red[4 + wave] = sq; }
  __syncthreads();
  s  = red[0] + red[1] + red[2] + red[3];
  sq = red[4] + red[5] + red[6] + red[7];
  const float mu   = s * (1.0f / 1024.0f);
  const float rstd = rsqrtf(sq * (1.0f / 1024.0f) - mu * mu + 1e-5f);
  const float4 gv = reinterpret_cast<const float4*>(g)[tid];
  const float4 bv = reinterpret_cast<const float4*>(b)[tid];
  ushort4 o;
  o.x = f2bf((v.x - mu) * rstd * gv.x + bv.x);
  o.y = f2bf((v.y - mu) * rstd * gv.y + bv.y);
  o.z = f2bf((v.z - mu) * rstd * gv.z + bv.z);
  o.w = f2bf((v.w - mu) * rstd * gv.w + bv.w);
  reinterpret_cast<ushort4*>(out)[row * 256 + tid] = o;
}

// ---------------- W[K][N] fp32 -> Wt[N][K] bf16 (tiled transpose+convert) ----------------
__global__ __launch_bounds__(256) void transpose_bf16_kernel(
    const float* __restrict__ W, u16* __restrict__ Wt, int K, int N) {
  __shared__ float tile[32][33];
  const int n0 = blockIdx.x * 32, k0 = blockIdx.y * 32;
  const int tx = threadIdx.x & 31;
  const int ty = threadIdx.x >> 5;  // 0..7
#pragma unroll
  for (int i = 0; i < 4; ++i)
    tile[ty + 8 * i][tx] = W[(k0 + ty + 8 * i) * (size_t)N + n0 + tx];
  __syncthreads();
#pragma unroll
  for (int i = 0; i < 4; ++i)
    Wt[(n0 + ty + 8 * i) * (size_t)K + k0 + tx] = f2bf(tile[tx][ty + 8 * i]);
}

// ---------------- bf16 MFMA GEMM: C[M,N] = A[M,K] @ Bt[N,K]^T, fused epilogues -------------
// Tile: BM x 128, BK=64. LDS layout XOR-swizzled: element (row, kc8) of a tile
// (kc8 = 8-elem k-chunk 0..7) lives at row*64 + (kc8 ^ (row&7))*8 — conflict-free
// ds_read_b128 and legal with global_load_lds (per-lane GLOBAL addr is free, LDS
// dest fixed at base+lane*16). XCD swizzle: flat%8 = XCD owns a bm-group.
// MODE 0: +bias, gelu -> bf16 out                      (fc)
// MODE 1: +bias, +resid(fp32) -> fp32                  (proj, fc2)
// MODE 3: +bias, scatter q(scaled)/k [B,H,T,HD], v transposed [B,H,HD,T]  (qkv)
template <int MODE, int BM>
__global__ __launch_bounds__(256, 2) void gemm_kernel(
    const u16* __restrict__ A, const u16* __restrict__ Bt,
    const float* __restrict__ bias, const float* __restrict__ resid,
    float* __restrict__ outf, u16* __restrict__ outb,
    u16* __restrict__ qo, u16* __restrict__ ko, u16* __restrict__ vto,
    int M, int N, int K, int logPer) {
  constexpr int MT = BM / 32;            // m-tiles of 16 per wave
  constexpr int AI = BM / 32;            // A staging instrs per wave (8 rows each)
  __shared__ __align__(16) u16 As[BM * 64];
  __shared__ __align__(16) u16 Bs[128 * 64];
  const int tid  = threadIdx.x;
  const int wave = tid >> 6, lane = tid & 63;
  const int col  = lane & 15, quad = lane >> 4;
  const int wm   = wave >> 1, wn = wave & 1;

  // XCD-aware swizzle: consecutive flat ids round-robin XCDs; give each XCD a
  // contiguous group of bm rows so A-tiles stay resident in one L2.
  const int flat = blockIdx.y * gridDim.x + blockIdx.x;
  const int xcd = flat & 7, sl = flat >> 3;
  const int per = 1 << logPer;
  const int bm = (xcd << logPer) + (sl & (per - 1));
  const int bn = sl >> logPer;

  // staging: srow = row-in-group (0..7), sc8 = physical 8-elem k-slot (0..7)
  const int srow = lane >> 3, sc8 = lane & 7;
  const int kcs = (sc8 ^ srow) * 8;                  // XOR-swizzled global k offset
  const u16* ap = A  + (size_t)(bm * BM + wave * (BM / 4) + srow) * K + kcs;
  const u16* bp = Bt + (size_t)(bn * 128 + wave * 32 + srow) * K + kcs;
  u16* as_dst = As + wave * (BM / 4) * 64;
  u16* bs_dst = Bs + wave * 2048;

  f32x4 acc[MT][4] = {};

  for (int k0 = 0; k0 < K; k0 += 64) {
    __syncthreads();
#pragma unroll
    for (int i = 0; i < AI; ++i)
      async_cp16(ap + k0 + i * 8 * (size_t)K, as_dst + i * 512);
#pragma unroll
    for (int i = 0; i < 4; ++i)
      async_cp16(bp + k0 + i * 8 * (size_t)K, bs_dst + i * 512);
    __syncthreads();
#pragma unroll
    for (int kh = 0; kh < 2; ++kh) {
      const int ks = kh * 4;
      bf16x8 af[MT], bf[4];
#pragma unroll
      for (int mt = 0; mt < MT; ++mt) {
        const int row = wm * (BM / 2) + mt * 16 + col;
        af[mt] = *reinterpret_cast<const bf16x8*>(&As[row * 64 + ((ks + quad) ^ (col & 7)) * 8]);
      }
#pragma unroll
      for (int nt = 0; nt < 4; ++nt) {
        const int row = wn * 64 + nt * 16 + col;
        bf[nt] = *reinterpret_cast<const bf16x8*>(&Bs[row * 64 + ((ks + quad) ^ (col & 7)) * 8]);
      }
#pragma unroll
      for (int mt = 0; mt < MT; ++mt)
#pragma unroll
        for (int nt = 0; nt < 4; ++nt)
          acc[mt][nt] = __builtin_amdgcn_mfma_f32_16x16x32_bf16(af[mt], bf[nt], acc[mt][nt], 0, 0, 0);
    }
  }

#pragma unroll
  for (int mt = 0; mt < MT; ++mt) {
#pragma unroll
    for (int r = 0; r < 4; ++r) {
      const int grow = bm * BM + wm * (BM / 2) + mt * 16 + quad * 4 + r;
#pragma unroll
      for (int nt = 0; nt < 4; ++nt) {
        const int gcol = bn * 128 + wn * 64 + nt * 16 + col;
        const float val = acc[mt][nt][r] + bias[gcol];
        if constexpr (MODE == 0) {
          outb[(size_t)grow * N + gcol] = f2bf(gelu_f(val));
        } else if constexpr (MODE == 1) {
          outf[(size_t)grow * N + gcol] = resid[(size_t)grow * N + gcol] + val;
        } else {
          const int which = gcol >> 10, c = gcol & 1023;
          const int hh = c >> 6, dd = c & 63;
          const int bb = grow >> 11, tt = grow & 2047;
          if (which == 0)
            qo[((bb * H_ + hh) * (size_t)T_ + tt) * HD_ + dd] = f2bf(val * 0.125f);
          else if (which == 1)
            ko[((bb * H_ + hh) * (size_t)T_ + tt) * HD_ + dd] = f2bf(val);
          else
            vto[((bb * H_ + hh) * (size_t)HD_ + dd) * T_ + tt] = f2bf(val);
        }
      }
    }
  }
}

// ---------------- flash attention (causal), bf16 MFMA, no-max online softmax ----------------
// grid: (B*H, T/64); block 256 = 4 waves, each wave owns 16 q rows. 64-key chunks,
// software-pipelined staging (next chunk's global loads fly during current compute).
// Row-sum via ones-MFMA (exp-safe: q pre-scaled 1/8). LDS rows padded to 68.
#define PSTR 68
__global__ __launch_bounds__(256, 4) void attn_kernel(
    const u16* __restrict__ q, const u16* __restrict__ k,
    const u16* __restrict__ vt, u16* __restrict__ y) {
  const int bh  = blockIdx.x;
  const int qt  = (T_ / 64 - 1) - blockIdx.y;
  const int tid = threadIdx.x;
  const int wave = tid >> 6, lane = tid & 63;
  const int col = lane & 15, quad = lane >> 4;
  const int b = bh >> 4, h = bh & 15;
  const int r0w = qt * 64 + wave * 16;   // wave's 16 q rows

  __shared__ __align__(16) u16 Klds[64 * PSTR];     // [key][d]
  __shared__ __align__(16) u16 Vtlds[64 * PSTR];    // [d][key]
  __shared__ __align__(16) u16 Plds[4 * 16 * PSTR]; // per-wave [qrow][key]

  bf16x8 aq[2];
#pragma unroll
  for (int j = 0; j < 2; ++j)
    aq[j] = *reinterpret_cast<const bf16x8*>(
        &q[((size_t)bh * T_ + r0w + col) * HD_ + j * 32 + quad * 8]);

  bf16x8 ones;
#pragma unroll
  for (int jj = 0; jj < 8; ++jj) ones[jj] = (__bf16)1.0f;

  f32x4 o[4] = {};
  f32x4 l_acc = {};

  const int srow = tid >> 3, spart = tid & 7;   // 32 rows x 8 parts
  u16* pw = Plds + wave * 16 * PSTR;
  const u16* kbase  = k  + (size_t)bh * T_ * HD_ + srow * HD_ + spart * 8;
  const u16* vtbase = vt + (size_t)bh * HD_ * T_ + srow * T_ + spart * 8;

  const int kb_last = qt * 64;

  uint4 kv0, kv1, kv2, kv3;
  // prefetch chunk 0
  kv0 = *reinterpret_cast<const uint4*>(kbase);
  kv1 = *reinterpret_cast<const uint4*>(kbase + 32 * HD_);
  kv2 = *reinterpret_cast<const uint4*>(vtbase);
  kv3 = *reinterpret_cast<const uint4*>(vtbase + 32 * T_);

  for (int kb = 0; kb <= kb_last; kb += 64) {
    // write staged regs to LDS
    *reinterpret_cast<uint4*>(&Klds[srow * PSTR + spart * 8])        = kv0;
    *reinterpret_cast<uint4*>(&Klds[(srow + 32) * PSTR + spart * 8]) = kv1;
    *reinterpret_cast<uint4*>(&Vtlds[srow * PSTR + spart * 8])        = kv2;
    *reinterpret_cast<uint4*>(&Vtlds[(srow + 32) * PSTR + spart * 8]) = kv3;
    __syncthreads();

    // issue next chunk's global loads (latency hidden behind compute below)
    if (kb < kb_last) {
      const int nk = kb + 64;
      kv0 = *reinterpret_cast<const uint4*>(kbase + (size_t)nk * HD_);
      kv1 = *reinterpret_cast<const uint4*>(kbase + (size_t)nk * HD_ + 32 * HD_);
      kv2 = *reinterpret_cast<const uint4*>(vtbase + nk);
      kv3 = *reinterpret_cast<const uint4*>(vtbase + 32 * T_ + nk);
    }

    // QK^T: 16 rows x 64 keys
    f32x4 s[4];
#pragma unroll
    for (int n = 0; n < 4; ++n) {
      const bf16x8 bk0 = *reinterpret_cast<const bf16x8*>(&Klds[(n * 16 + col) * PSTR + quad * 8]);
      const bf16x8 bk1 = *reinterpret_cast<const bf16x8*>(&Klds[(n * 16 + col) * PSTR + 32 + quad * 8]);
      f32x4 z = {};
      z = __builtin_amdgcn_mfma_f32_16x16x32_bf16(aq[0], bk0, z, 0, 0, 0);
      s[n] = __builtin_amdgcn_mfma_f32_16x16x32_bf16(aq[1], bk1, z, 0, 0, 0);
    }

    // exp + causal mask (only the final/diagonal chunk needs masking); write P
    const bool domask = (kb == kb_last);
#pragma unroll
    for (int n = 0; n < 4; ++n) {
#pragma unroll
      for (int r = 0; r < 4; ++r) {
        float sv = s[n][r];
        if (domask) {
          const int key = kb + n * 16 + col;
          const int row = r0w + quad * 4 + r;
          sv = (key <= row) ? sv : -1e30f;
        }
        pw[(quad * 4 + r) * PSTR + n * 16 + col] = f2bf(__expf(sv));
      }
    }
    __builtin_amdgcn_s_waitcnt(0xC07F);  // lgkmcnt(0): own-wave P writes visible

    const bf16x8 ap0 = *reinterpret_cast<const bf16x8*>(&pw[col * PSTR + quad * 8]);
    const bf16x8 ap1 = *reinterpret_cast<const bf16x8*>(&pw[col * PSTR + 32 + quad * 8]);
    l_acc = __builtin_amdgcn_mfma_f32_16x16x32_bf16(ap0, ones, l_acc, 0, 0, 0);
    l_acc = __builtin_amdgcn_mfma_f32_16x16x32_bf16(ap1, ones, l_acc, 0, 0, 0);
#pragma unroll
    for (int n = 0; n < 4; ++n) {
      const bf16x8 bv0 = *reinterpret_cast<const bf16x8*>(&Vtlds[(n * 16 + col) * PSTR + quad * 8]);
      const bf16x8 bv1 = *reinterpret_cast<const bf16x8*>(&Vtlds[(n * 16 + col) * PSTR + 32 + quad * 8]);
      o[n] = __builtin_amdgcn_mfma_f32_16x16x32_bf16(ap0, bv0, o[n], 0, 0, 0);
      o[n] = __builtin_amdgcn_mfma_f32_16x16x32_bf16(ap1, bv1, o[n], 0, 0, 0);
    }
    __syncthreads();  // all waves done reading K/V before next chunk's ds_write
  }

#pragma unroll
  for (int r = 0; r < 4; ++r) {
    const int qrow = r0w + quad * 4 + r;
    const float inv = 1.0f / l_acc[r];
#pragma unroll
    for (int n = 0; n < 4; ++n)
      y[((size_t)b * T_ + qrow) * C_ + h * HD_ + n * 16 + col] = f2bf(o[n][r] * inv);
  }
}

extern "C" void kernel_launch(void* const* d_in, const int* in_sizes, int n_in,
                              void* d_out, int out_size, void* d_ws, size_t ws_size,
                              hipStream_t stream) {
  const float* x      = (const float*)d_in[0];
  const float* ln1_g  = (const float*)d_in[1];
  const float* ln1_b  = (const float*)d_in[2];
  const float* W_attn = (const float*)d_in[3];
  const float* b_attn = (const float*)d_in[4];
  const float* W_proj = (const float*)d_in[5];
  const float* b_proj = (const float*)d_in[6];
  const float* ln2_g  = (const float*)d_in[7];
  const float* ln2_b  = (const float*)d_in[8];
  const float* W_fc   = (const float*)d_in[9];
  const float* b_fc   = (const float*)d_in[10];
  const float* W_fc2  = (const float*)d_in[11];
  const float* b_fc2  = (const float*)d_in[12];
  float* out = (float*)d_out;

  char* p = (char*)d_ws;
  auto alloc = [&](size_t bytes) {
    char* r = p;
    p += (bytes + 255) & ~(size_t)255;
    return r;
  };
  u16*   h1      = (u16*)alloc((size_t)M_TOT * C_ * 2);
  u16*   wt_attn = (u16*)alloc((size_t)3 * C_ * C_ * 2);
  u16*   wt_proj = (u16*)alloc((size_t)C_ * C_ * 2);
  u16*   wt_fc   = (u16*)alloc((size_t)4 * C_ * C_ * 2);
  u16*   wt_fc2  = (u16*)alloc((size_t)C_ * 4 * C_ * 2);
  u16*   qbuf    = (u16*)alloc((size_t)M_TOT * C_ * 2);
  u16*   kbuf    = (u16*)alloc((size_t)M_TOT * C_ * 2);
  u16*   vtbuf   = (u16*)alloc((size_t)M_TOT * C_ * 2);
  u16*   ybuf    = (u16*)alloc((size_t)M_TOT * C_ * 2);
  float* x2      = (float*)alloc((size_t)M_TOT * C_ * 4);
  u16*   h2      = (u16*)alloc((size_t)M_TOT * C_ * 2);
  u16*   act     = (u16*)alloc((size_t)M_TOT * 4 * C_ * 2);

  // weights: fp32 [K][N] -> bf16 [N][K]
  transpose_bf16_kernel<<<dim3(96, 32),  256, 0, stream>>>(W_attn, wt_attn, 1024, 3072);
  transpose_bf16_kernel<<<dim3(32, 32),  256, 0, stream>>>(W_proj, wt_proj, 1024, 1024);
  transpose_bf16_kernel<<<dim3(128, 32), 256, 0, stream>>>(W_fc,   wt_fc,   1024, 4096);
  transpose_bf16_kernel<<<dim3(32, 128), 256, 0, stream>>>(W_fc2,  wt_fc2,  4096, 1024);

  // ln1
  ln_bf16_kernel<<<M_TOT, 256, 0, stream>>>(x, ln1_g, ln1_b, h1);

  // qkv = h1 @ W_attn + b_attn -> q(scaled)/k/vt   (768 blocks; 32 bm rows -> logPer=2)
  gemm_kernel<3, 128><<<dim3(24, 32), 256, 0, stream>>>(h1, wt_attn, b_attn, nullptr,
                                                        nullptr, nullptr, qbuf, kbuf, vtbuf,
                                                        4096, 3072, 1024, 2);
  // causal flash attention -> y [B,T,C]   (1024 blocks, 64-row q-tiles)
  attn_kernel<<<dim3(32, 32), 256, 0, stream>>>(qbuf, kbuf, vtbuf, ybuf);

  // x2 = x + y @ W_proj + b_proj    (64x128 tile, 512 blocks; 64 bm rows -> logPer=3)
  gemm_kernel<1, 64><<<dim3(8, 64), 256, 0, stream>>>(ybuf, wt_proj, b_proj, x,
                                                      x2, nullptr, nullptr, nullptr, nullptr,
                                                      4096, 1024, 1024, 3);
  // ln2
  ln_bf16_kernel<<<M_TOT, 256, 0, stream>>>(x2, ln2_g, ln2_b, h2);

  // act = gelu(h2 @ W_fc + b_fc)    (1024 blocks; 32 bm rows -> logPer=2)
  gemm_kernel<0, 128><<<dim3(32, 32), 256, 0, stream>>>(h2, wt_fc, b_fc, nullptr,
                                                        nullptr, act, nullptr, nullptr, nullptr,
                                                        4096, 4096, 1024, 2);
  // out = x2 + act @ W_fc2 + b_fc2  (64x128 tile, 512 blocks; 64 bm rows -> logPer=3)
  gemm_kernel<1, 64><<<dim3(8, 64), 256, 0, stream>>>(act, wt_fc2, b_fc2, x2,
                                                      out, nullptr, nullptr, nullptr, nullptr,
                                                      4096, 1024, 4096, 3);
}